// Round 10
// baseline (289.706 us; speedup 1.0000x reference)
//
#include <hip/hip_runtime.h>
#include <math.h>

#define FDIM 128
#define NEG_SLOPE 0.2f

__device__ __forceinline__ float lrelu(float x) {
    return x > 0.f ? x : NEG_SLOPE * x;
}

// bf16 helpers (RNE; inputs finite)
__device__ __forceinline__ unsigned short f2bf(float f) {
    unsigned u = __float_as_uint(f);
    return (unsigned short)((u + 0x7FFFu + ((u >> 16) & 1u)) >> 16);
}
__device__ __forceinline__ float bf2f(unsigned short h) {
    return __uint_as_float((unsigned)h << 16);
}

// ================= atomic-free radix CSR build (unchanged from R9) =================

__global__ __launch_bounds__(256) void k_hist(const int* __restrict__ dstp,
                                              int E, int N,
                                              int* __restrict__ hist,
                                              int nb1, int nbuck) {
    __shared__ int hl[256];
    int t = threadIdx.x, blk = blockIdx.x;
    hl[t] = 0;
    __syncthreads();
    int total = E + N;
    int e0 = blk * 1024 + t * 4;
    if (e0 < total) {
        if (e0 + 3 < E) {
            int4 d4 = *(const int4*)(dstp + e0);
            atomicAdd(&hl[d4.x >> 8], 1);
            atomicAdd(&hl[d4.y >> 8], 1);
            atomicAdd(&hl[d4.z >> 8], 1);
            atomicAdd(&hl[d4.w >> 8], 1);
        } else {
#pragma unroll
            for (int q = 0; q < 4; ++q) {
                int e = e0 + q;
                if (e < total) {
                    int d = (e < E) ? dstp[e] : (e - E);
                    atomicAdd(&hl[d >> 8], 1);
                }
            }
        }
    }
    __syncthreads();
    if (t < nbuck) hist[t * nb1 + blk] = hl[t];
}

__global__ __launch_bounds__(256) void k_scan1(const int* __restrict__ in,
                                               int* __restrict__ out,
                                               int* __restrict__ bsum, int M) {
    __shared__ int sh[256];
    int b = blockIdx.x, t = threadIdx.x;
    int base = b * 1024 + t * 4;
    int4 v = make_int4(0, 0, 0, 0);
    if (base + 3 < M) v = *(const int4*)(in + base);
    else {
        if (base < M)     v.x = in[base];
        if (base + 1 < M) v.y = in[base + 1];
        if (base + 2 < M) v.z = in[base + 2];
        if (base + 3 < M) v.w = in[base + 3];
    }
    int s = v.x + v.y + v.z + v.w;
    sh[t] = s;
    __syncthreads();
    for (int off = 1; off < 256; off <<= 1) {
        int u = (t >= off) ? sh[t - off] : 0;
        __syncthreads();
        sh[t] += u;
        __syncthreads();
    }
    int excl = t ? sh[t - 1] : 0;
    if (base < M)     out[base]     = excl;
    if (base + 1 < M) out[base + 1] = excl + v.x;
    if (base + 2 < M) out[base + 2] = excl + v.x + v.y;
    if (base + 3 < M) out[base + 3] = excl + v.x + v.y + v.z;
    if (t == 255) bsum[b] = sh[255];
}

__global__ __launch_bounds__(256) void k_scan2(int* __restrict__ bsum, int nb) {
    __shared__ int sh[256];
    int t = threadIdx.x;
    int chunk = (nb + 255) >> 8;
    int b0 = t * chunk, b1 = min(b0 + chunk, nb);
    int s = 0;
    for (int i = b0; i < b1; ++i) s += bsum[i];
    sh[t] = s;
    __syncthreads();
    for (int off = 1; off < 256; off <<= 1) {
        int u = (t >= off) ? sh[t - off] : 0;
        __syncthreads();
        sh[t] += u;
        __syncthreads();
    }
    int run = t ? sh[t - 1] : 0;
    for (int i = b0; i < b1; ++i) { int v = bsum[i]; bsum[i] = run; run += v; }
}

__global__ __launch_bounds__(256) void k_scan3(int* __restrict__ out,
                                               const int* __restrict__ bsum, int M) {
    int i = blockIdx.x * 256 + threadIdx.x;
    if (i < M) out[i] += bsum[i >> 10];
}

__global__ __launch_bounds__(256) void k_scatter(const int* __restrict__ srcp,
                                                 const int* __restrict__ dstp,
                                                 int E, int N,
                                                 const int* __restrict__ histScan,
                                                 int nb1, int nbuck,
                                                 int* __restrict__ part) {
    __shared__ int baseL[256];
    __shared__ int runL[256];
    int t = threadIdx.x, blk = blockIdx.x;
    if (t < nbuck) baseL[t] = histScan[t * nb1 + blk];
    runL[t] = 0;
    __syncthreads();
    int total = E + N;
    int e0 = blk * 1024 + t * 4;
    if (e0 >= total) return;
    if (e0 + 3 < E) {
        int4 s4 = *(const int4*)(srcp + e0);
        int4 d4 = *(const int4*)(dstp + e0);
        int r, bin;
        bin = d4.x >> 8; r = atomicAdd(&runL[bin], 1);
        part[baseL[bin] + r] = (s4.x << 8) | (d4.x & 255);
        bin = d4.y >> 8; r = atomicAdd(&runL[bin], 1);
        part[baseL[bin] + r] = (s4.y << 8) | (d4.y & 255);
        bin = d4.z >> 8; r = atomicAdd(&runL[bin], 1);
        part[baseL[bin] + r] = (s4.z << 8) | (d4.z & 255);
        bin = d4.w >> 8; r = atomicAdd(&runL[bin], 1);
        part[baseL[bin] + r] = (s4.w << 8) | (d4.w & 255);
    } else {
#pragma unroll
        for (int q = 0; q < 4; ++q) {
            int e = e0 + q;
            if (e < total) {
                int s, d;
                if (e < E) { s = srcp[e]; d = dstp[e]; }
                else       { s = d = e - E; }
                int bin = d >> 8;
                int r = atomicAdd(&runL[bin], 1);
                part[baseL[bin] + r] = (s << 8) | (d & 255);
            }
        }
    }
}

__global__ __launch_bounds__(256) void k_bucket(const int* __restrict__ part,
                                                const int* __restrict__ histScan,
                                                int nb1, int nbuck, int E2, int N,
                                                int* __restrict__ rowp,
                                                int* __restrict__ col) {
    __shared__ int cntL[256];
    __shared__ int exclL[256];
    __shared__ int sh[256];
    int b = blockIdx.x, t = threadIdx.x;
    int s0 = histScan[b * nb1];
    int s1 = (b == nbuck - 1) ? E2 : histScan[(b + 1) * nb1];

    cntL[t] = 0;
    __syncthreads();
    for (int i = s0 + t; i < s1; i += 256)
        atomicAdd(&cntL[part[i] & 255], 1);
    __syncthreads();

    sh[t] = cntL[t];
    __syncthreads();
    for (int off = 1; off < 256; off <<= 1) {
        int u = (t >= off) ? sh[t - off] : 0;
        __syncthreads();
        sh[t] += u;
        __syncthreads();
    }
    exclL[t] = t ? sh[t - 1] : 0;
    __syncthreads();

    int d = b * 256 + t;
    if (d < N) rowp[d] = s0 + exclL[t];
    if (b == nbuck - 1 && t == 0) rowp[N] = E2;

    cntL[t] = 0;
    __syncthreads();
    for (int i = s0 + t; i < s1; i += 256) {
        int p = part[i];
        int dl = p & 255;
        int r = atomicAdd(&cntL[dl], 1);
        col[s0 + exclL[dl] + r] = (int)((unsigned)p >> 8);
    }
}

// ---------------- GEMM (+ fused attention scalars): 64 rows/block ----------------
// W read straight from global (64KB, L2-resident, shared by all blocks) — no
// 64KB LDS tile, so occupancy is VGPR-limited (~5 waves/SIMD) instead of
// 2 blocks/CU (R7/R9 lesson: big LDS kills latency hiding).

__global__ __launch_bounds__(256) void k_gemm(const float* __restrict__ A,
                                              const float* __restrict__ W,
                                              unsigned short* __restrict__ out,
                                              const float* __restrict__ att_s,
                                              const float* __restrict__ att_d,
                                              float* __restrict__ asrc,
                                              float* __restrict__ adst, int nrows) {
    __shared__ float sAs[FDIM], sAd[FDIM];
    int t = threadIdx.x;
    if (t < FDIM) { sAs[t] = att_s[t]; sAd[t] = att_d[t]; }
    __syncthreads();

    int tx = t & 31;
    int ty = t >> 5;
    int row0 = blockIdx.x * 64 + ty * 8;
    const float4* __restrict__ W4 = (const float4*)W;

    float acc[8][4];
#pragma unroll
    for (int i = 0; i < 8; ++i)
#pragma unroll
        for (int j = 0; j < 4; ++j) acc[i][j] = 0.f;

    int rr[8];
#pragma unroll
    for (int i = 0; i < 8; ++i)
        rr[i] = (row0 + i < nrows) ? (row0 + i) : (nrows - 1);

#pragma unroll 2
    for (int k4 = 0; k4 < FDIM; k4 += 4) {
        float4 xv[8];
#pragma unroll
        for (int i = 0; i < 8; ++i)
            xv[i] = *(const float4*)(A + (size_t)rr[i] * FDIM + k4);
#pragma unroll
        for (int q = 0; q < 4; ++q) {
            float4 wv = W4[(k4 + q) * 32 + tx];
#pragma unroll
            for (int i = 0; i < 8; ++i) {
                float xs = (q == 0) ? xv[i].x : (q == 1) ? xv[i].y : (q == 2) ? xv[i].z : xv[i].w;
                acc[i][0] = fmaf(xs, wv.x, acc[i][0]);
                acc[i][1] = fmaf(xs, wv.y, acc[i][1]);
                acc[i][2] = fmaf(xs, wv.z, acc[i][2]);
                acc[i][3] = fmaf(xs, wv.w, acc[i][3]);
            }
        }
    }
#pragma unroll
    for (int i = 0; i < 8; ++i) {
        if (row0 + i < nrows) {
            ushort4 o;
            o.x = f2bf(acc[i][0]);
            o.y = f2bf(acc[i][1]);
            o.z = f2bf(acc[i][2]);
            o.w = f2bf(acc[i][3]);
            *(ushort4*)(out + (size_t)(row0 + i) * FDIM + tx * 4) = o;
        }
    }

    float ps[8], pd[8];
#pragma unroll
    for (int i = 0; i < 8; ++i) {
        float s = 0.f, d = 0.f;
#pragma unroll
        for (int j = 0; j < 4; ++j) {
            s = fmaf(acc[i][j], sAs[tx * 4 + j], s);
            d = fmaf(acc[i][j], sAd[tx * 4 + j], d);
        }
        ps[i] = s; pd[i] = d;
    }
#pragma unroll
    for (int off = 8; off; off >>= 1) {
#pragma unroll
        for (int i = 0; i < 8; ++i) {
            ps[i] += __shfl_xor(ps[i], off);
            pd[i] += __shfl_xor(pd[i], off);
        }
    }
    if ((tx & 15) == 0) {
        int head = tx >> 4;
#pragma unroll
        for (int i = 0; i < 8; ++i) {
            if (row0 + i < nrows) {
                asrc[2 * (row0 + i) + head] = ps[i];
                adst[2 * (row0 + i) + head] = pd[i];
            }
        }
    }
}

// ---------------- per-dst softmax + aggregation: ONE WAVE PER NODE ----------------
// Zero LDS: chunk state lives in registers; edge index + unnormalized alphas are
// broadcast per-edge via v_readlane (uniform) — the gather address becomes
// SGPR-base + constant lane offset, killing the per-edge 64-bit VALU addr chain.

__global__ __launch_bounds__(256) void k_aggregate(const unsigned short* __restrict__ h,
                                                   const float* __restrict__ asrc,
                                                   const float* __restrict__ adst,
                                                   const int* __restrict__ rowp,
                                                   const int* __restrict__ col,
                                                   const float* __restrict__ bias,
                                                   float* __restrict__ outbuf,
                                                   const float* __restrict__ fcW,
                                                   const float* __restrict__ fcb,
                                                   float* __restrict__ outfin, int n) {
    int t = threadIdx.x;
    int w = t >> 6;
    int lane = t & 63;
    int node = blockIdx.x * 4 + w;      // uniform per wave
    if (node >= n) return;

    int start = rowp[node];
    int deg = rowp[node + 1] - start;
    float2 adv = *(const float2*)(adst + 2 * node);
    const ushort2* __restrict__ hb = (const ushort2*)h;
    bool head1 = lane >= 32;

    float m0 = -1e30f, m1 = -1e30f;
    float p0 = 0.f, p1 = 0.f;
    float accx = 0.f, accy = 0.f;

    for (int base = 0; base < deg; base += 64) {
        int cnt = min(64, deg - base);
        int s = 0;
        float v0 = -1e30f, v1 = -1e30f;
        if (lane < cnt) {
            s = col[start + base + lane];
            float2 av = *(const float2*)(asrc + 2 * s);
            v0 = lrelu(av.x + adv.x);
            v1 = lrelu(av.y + adv.y);
        }
        // chunk max (in-wave)
        float c0 = v0, c1 = v1;
#pragma unroll
        for (int off = 32; off; off >>= 1) {
            c0 = fmaxf(c0, __shfl_xor(c0, off));
            c1 = fmaxf(c1, __shfl_xor(c1, off));
        }
        float nm0 = fmaxf(m0, c0), nm1 = fmaxf(m1, c1);
        float r0 = __expf(m0 - nm0), r1 = __expf(m1 - nm1);
        m0 = nm0; m1 = nm1;
        p0 *= r0; p1 *= r1;
        float rmy = head1 ? r1 : r0;
        accx *= rmy; accy *= rmy;
        // unnormalized alphas (kept in registers; lane i holds edge i's values)
        float e0 = (lane < cnt) ? __expf(v0 - m0) : 0.f;
        float e1 = (lane < cnt) ? __expf(v1 - m1) : 0.f;
        p0 += e0; p1 += e1;
        int ie0 = __float_as_int(e0);
        int ie1 = __float_as_int(e1);

        // gather: readlane broadcasts, 4 independent load chains
        float2 g0 = make_float2(0.f, 0.f), g1 = make_float2(0.f, 0.f);
        float2 g2 = make_float2(0.f, 0.f), g3 = make_float2(0.f, 0.f);
        int i = 0;
        for (; i + 3 < cnt; i += 4) {
            unsigned sa = (unsigned)__builtin_amdgcn_readlane(s, i);
            unsigned sb = (unsigned)__builtin_amdgcn_readlane(s, i + 1);
            unsigned sc = (unsigned)__builtin_amdgcn_readlane(s, i + 2);
            unsigned sd = (unsigned)__builtin_amdgcn_readlane(s, i + 3);
            ushort2 ha = hb[sa * 64u + lane];
            ushort2 hv = hb[sb * 64u + lane];
            ushort2 hc = hb[sc * 64u + lane];
            ushort2 hd = hb[sd * 64u + lane];
            float wa = head1 ? __int_as_float(__builtin_amdgcn_readlane(ie1, i))
                             : __int_as_float(__builtin_amdgcn_readlane(ie0, i));
            float wb = head1 ? __int_as_float(__builtin_amdgcn_readlane(ie1, i + 1))
                             : __int_as_float(__builtin_amdgcn_readlane(ie0, i + 1));
            float wc = head1 ? __int_as_float(__builtin_amdgcn_readlane(ie1, i + 2))
                             : __int_as_float(__builtin_amdgcn_readlane(ie0, i + 2));
            float wd = head1 ? __int_as_float(__builtin_amdgcn_readlane(ie1, i + 3))
                             : __int_as_float(__builtin_amdgcn_readlane(ie0, i + 3));
            g0.x = fmaf(bf2f(ha.x), wa, g0.x); g0.y = fmaf(bf2f(ha.y), wa, g0.y);
            g1.x = fmaf(bf2f(hv.x), wb, g1.x); g1.y = fmaf(bf2f(hv.y), wb, g1.y);
            g2.x = fmaf(bf2f(hc.x), wc, g2.x); g2.y = fmaf(bf2f(hc.y), wc, g2.y);
            g3.x = fmaf(bf2f(hd.x), wd, g3.x); g3.y = fmaf(bf2f(hd.y), wd, g3.y);
        }
        for (; i < cnt; ++i) {
            unsigned sv = (unsigned)__builtin_amdgcn_readlane(s, i);
            float a = head1 ? __int_as_float(__builtin_amdgcn_readlane(ie1, i))
                            : __int_as_float(__builtin_amdgcn_readlane(ie0, i));
            ushort2 hv = hb[sv * 64u + lane];
            g0.x = fmaf(bf2f(hv.x), a, g0.x);
            g0.y = fmaf(bf2f(hv.y), a, g0.y);
        }
        accx += g0.x + g1.x + g2.x + g3.x;
        accy += g0.y + g1.y + g2.y + g3.y;
    }

#pragma unroll
    for (int off = 32; off; off >>= 1) {
        p0 += __shfl_xor(p0, off);
        p1 += __shfl_xor(p1, off);
    }
    float invmy = head1 ? 1.f / (p1 + 1e-16f) : 1.f / (p0 + 1e-16f);
    accx *= invmy;
    accy *= invmy;

    int c0i = 2 * lane, c1i = 2 * lane + 1;
    float2 bv = *(const float2*)(bias + c0i);
    float o0 = fmaxf(accx + bv.x, 0.f);
    float o1 = fmaxf(accy + bv.y, 0.f);
    if (outbuf)
        *(float2*)(outbuf + (size_t)node * FDIM + c0i) = make_float2(o0, o1);
    if (outfin) {
        float2 fv = *(const float2*)(fcW + c0i);
        float p = fmaf(o0, fv.x, o1 * fv.y);
#pragma unroll
        for (int off = 32; off; off >>= 1) p += __shfl_xor(p, off);
        if (lane == 0) outfin[node] = 1.f / (1.f + __expf(-(p + fcb[0])));
    }
}

// ---------------- host ----------------

static inline size_t rnd256(size_t x) { return (x + 255) & ~(size_t)255; }

extern "C" void kernel_launch(void* const* d_in, const int* in_sizes, int n_in,
                              void* d_out, int out_size, void* d_ws, size_t ws_size,
                              hipStream_t stream) {
    const float* x    = (const float*)d_in[0];
    const int*   ei   = (const int*)d_in[1];
    const float* W1   = (const float*)d_in[3];
    const float* as1  = (const float*)d_in[4];
    const float* ad1  = (const float*)d_in[5];
    const float* b1   = (const float*)d_in[6];
    const float* W2   = (const float*)d_in[7];
    const float* as2  = (const float*)d_in[8];
    const float* ad2  = (const float*)d_in[9];
    const float* b2   = (const float*)d_in[10];
    const float* fcW  = (const float*)d_in[11];
    const float* fcb  = (const float*)d_in[12];

    int N = in_sizes[0] / FDIM;
    int E = in_sizes[2];
    int E2 = E + N;
    const int* srcp = ei;
    const int* dstp = ei + E;

    int nb1   = (E2 + 1023) / 1024;        // radix blocks (1024 edges each)
    int nbuck = (N + 255) / 256;           // coarse buckets (256 dsts each)
    int M     = nbuck * nb1;               // hist entries

    char* w = (char*)d_ws;
    unsigned short* hbuf = (unsigned short*)w; w += rnd256((size_t)N * FDIM * sizeof(unsigned short));
    float* obuf = (float*)w;  w += rnd256((size_t)N * FDIM * sizeof(float));
    float* asrc = (float*)w;  w += rnd256((size_t)N * 2 * sizeof(float));
    float* adst = (float*)w;  w += rnd256((size_t)N * 2 * sizeof(float));
    int* rowp = (int*)w;      w += rnd256((size_t)(N + 1) * sizeof(int));
    int* bsum = (int*)w;      w += rnd256((size_t)((M + 1023) / 1024) * sizeof(int));
    int* hist = (int*)w;      w += rnd256((size_t)M * sizeof(int));
    int* part = (int*)w;      w += rnd256((size_t)E2 * sizeof(int));
    int* col  = (int*)w;      w += rnd256((size_t)E2 * sizeof(int));

    int ggrid = (N + 63) / 64;
    int agrid = (N + 3) / 4;
    int sblk  = (M + 1023) / 1024;

    // atomic-free CSR build
    k_hist<<<nb1, 256, 0, stream>>>(dstp, E, N, hist, nb1, nbuck);
    k_scan1<<<sblk, 256, 0, stream>>>(hist, hist, bsum, M);
    k_scan2<<<1, 256, 0, stream>>>(bsum, sblk);
    k_scan3<<<(M + 255) / 256, 256, 0, stream>>>(hist, bsum, M);
    k_scatter<<<nb1, 256, 0, stream>>>(srcp, dstp, E, N, hist, nb1, nbuck, part);
    k_bucket<<<nbuck, 256, 0, stream>>>(part, hist, nb1, nbuck, E2, N, rowp, col);

    // layer 1 (gemm + fused att scalars; bf16 h)
    k_gemm<<<ggrid, 256, 0, stream>>>(x, W1, hbuf, as1, ad1, asrc, adst, N);
    k_aggregate<<<agrid, 256, 0, stream>>>(hbuf, asrc, adst, rowp, col, b1,
                                           obuf, nullptr, nullptr, nullptr, N);

    // layer 2 (fc + sigmoid fused into epilogue)
    k_gemm<<<ggrid, 256, 0, stream>>>(obuf, W2, hbuf, as2, ad2, asrc, adst, N);
    k_aggregate<<<agrid, 256, 0, stream>>>(hbuf, asrc, adst, rowp, col, b2,
                                           nullptr, fcW, fcb, (float*)d_out, N);
}

// Round 11
// 258.476 us; speedup vs baseline: 1.1208x; 1.1208x over previous
//
#include <hip/hip_runtime.h>
#include <math.h>

#define FDIM 128
#define NEG_SLOPE 0.2f

__device__ __forceinline__ float lrelu(float x) {
    return x > 0.f ? x : NEG_SLOPE * x;
}

// bf16 helpers (RNE; inputs finite)
__device__ __forceinline__ unsigned short f2bf(float f) {
    unsigned u = __float_as_uint(f);
    return (unsigned short)((u + 0x7FFFu + ((u >> 16) & 1u)) >> 16);
}
__device__ __forceinline__ float bf2f(unsigned short h) {
    return __uint_as_float((unsigned)h << 16);
}

// ================= atomic-free radix CSR build (unchanged from R9) =================

__global__ __launch_bounds__(256) void k_hist(const int* __restrict__ dstp,
                                              int E, int N,
                                              int* __restrict__ hist,
                                              int nb1, int nbuck) {
    __shared__ int hl[256];
    int t = threadIdx.x, blk = blockIdx.x;
    hl[t] = 0;
    __syncthreads();
    int total = E + N;
    int e0 = blk * 1024 + t * 4;
    if (e0 < total) {
        if (e0 + 3 < E) {
            int4 d4 = *(const int4*)(dstp + e0);
            atomicAdd(&hl[d4.x >> 8], 1);
            atomicAdd(&hl[d4.y >> 8], 1);
            atomicAdd(&hl[d4.z >> 8], 1);
            atomicAdd(&hl[d4.w >> 8], 1);
        } else {
#pragma unroll
            for (int q = 0; q < 4; ++q) {
                int e = e0 + q;
                if (e < total) {
                    int d = (e < E) ? dstp[e] : (e - E);
                    atomicAdd(&hl[d >> 8], 1);
                }
            }
        }
    }
    __syncthreads();
    if (t < nbuck) hist[t * nb1 + blk] = hl[t];
}

__global__ __launch_bounds__(256) void k_scan1(const int* __restrict__ in,
                                               int* __restrict__ out,
                                               int* __restrict__ bsum, int M) {
    __shared__ int sh[256];
    int b = blockIdx.x, t = threadIdx.x;
    int base = b * 1024 + t * 4;
    int4 v = make_int4(0, 0, 0, 0);
    if (base + 3 < M) v = *(const int4*)(in + base);
    else {
        if (base < M)     v.x = in[base];
        if (base + 1 < M) v.y = in[base + 1];
        if (base + 2 < M) v.z = in[base + 2];
        if (base + 3 < M) v.w = in[base + 3];
    }
    int s = v.x + v.y + v.z + v.w;
    sh[t] = s;
    __syncthreads();
    for (int off = 1; off < 256; off <<= 1) {
        int u = (t >= off) ? sh[t - off] : 0;
        __syncthreads();
        sh[t] += u;
        __syncthreads();
    }
    int excl = t ? sh[t - 1] : 0;
    if (base < M)     out[base]     = excl;
    if (base + 1 < M) out[base + 1] = excl + v.x;
    if (base + 2 < M) out[base + 2] = excl + v.x + v.y;
    if (base + 3 < M) out[base + 3] = excl + v.x + v.y + v.z;
    if (t == 255) bsum[b] = sh[255];
}

__global__ __launch_bounds__(256) void k_scan2(int* __restrict__ bsum, int nb) {
    __shared__ int sh[256];
    int t = threadIdx.x;
    int chunk = (nb + 255) >> 8;
    int b0 = t * chunk, b1 = min(b0 + chunk, nb);
    int s = 0;
    for (int i = b0; i < b1; ++i) s += bsum[i];
    sh[t] = s;
    __syncthreads();
    for (int off = 1; off < 256; off <<= 1) {
        int u = (t >= off) ? sh[t - off] : 0;
        __syncthreads();
        sh[t] += u;
        __syncthreads();
    }
    int run = t ? sh[t - 1] : 0;
    for (int i = b0; i < b1; ++i) { int v = bsum[i]; bsum[i] = run; run += v; }
}

__global__ __launch_bounds__(256) void k_scan3(int* __restrict__ out,
                                               const int* __restrict__ bsum, int M) {
    int i = blockIdx.x * 256 + threadIdx.x;
    if (i < M) out[i] += bsum[i >> 10];
}

__global__ __launch_bounds__(256) void k_scatter(const int* __restrict__ srcp,
                                                 const int* __restrict__ dstp,
                                                 int E, int N,
                                                 const int* __restrict__ histScan,
                                                 int nb1, int nbuck,
                                                 int* __restrict__ part) {
    __shared__ int baseL[256];
    __shared__ int runL[256];
    int t = threadIdx.x, blk = blockIdx.x;
    if (t < nbuck) baseL[t] = histScan[t * nb1 + blk];
    runL[t] = 0;
    __syncthreads();
    int total = E + N;
    int e0 = blk * 1024 + t * 4;
    if (e0 >= total) return;
    if (e0 + 3 < E) {
        int4 s4 = *(const int4*)(srcp + e0);
        int4 d4 = *(const int4*)(dstp + e0);
        int r, bin;
        bin = d4.x >> 8; r = atomicAdd(&runL[bin], 1);
        part[baseL[bin] + r] = (s4.x << 8) | (d4.x & 255);
        bin = d4.y >> 8; r = atomicAdd(&runL[bin], 1);
        part[baseL[bin] + r] = (s4.y << 8) | (d4.y & 255);
        bin = d4.z >> 8; r = atomicAdd(&runL[bin], 1);
        part[baseL[bin] + r] = (s4.z << 8) | (d4.z & 255);
        bin = d4.w >> 8; r = atomicAdd(&runL[bin], 1);
        part[baseL[bin] + r] = (s4.w << 8) | (d4.w & 255);
    } else {
#pragma unroll
        for (int q = 0; q < 4; ++q) {
            int e = e0 + q;
            if (e < total) {
                int s, d;
                if (e < E) { s = srcp[e]; d = dstp[e]; }
                else       { s = d = e - E; }
                int bin = d >> 8;
                int r = atomicAdd(&runL[bin], 1);
                part[baseL[bin] + r] = (s << 8) | (d & 255);
            }
        }
    }
}

__global__ __launch_bounds__(256) void k_bucket(const int* __restrict__ part,
                                                const int* __restrict__ histScan,
                                                int nb1, int nbuck, int E2, int N,
                                                int* __restrict__ rowp,
                                                int* __restrict__ col) {
    __shared__ int cntL[256];
    __shared__ int exclL[256];
    __shared__ int sh[256];
    int b = blockIdx.x, t = threadIdx.x;
    int s0 = histScan[b * nb1];
    int s1 = (b == nbuck - 1) ? E2 : histScan[(b + 1) * nb1];

    cntL[t] = 0;
    __syncthreads();
    for (int i = s0 + t; i < s1; i += 256)
        atomicAdd(&cntL[part[i] & 255], 1);
    __syncthreads();

    sh[t] = cntL[t];
    __syncthreads();
    for (int off = 1; off < 256; off <<= 1) {
        int u = (t >= off) ? sh[t - off] : 0;
        __syncthreads();
        sh[t] += u;
        __syncthreads();
    }
    exclL[t] = t ? sh[t - 1] : 0;
    __syncthreads();

    int d = b * 256 + t;
    if (d < N) rowp[d] = s0 + exclL[t];
    if (b == nbuck - 1 && t == 0) rowp[N] = E2;

    cntL[t] = 0;
    __syncthreads();
    for (int i = s0 + t; i < s1; i += 256) {
        int p = part[i];
        int dl = p & 255;
        int r = atomicAdd(&cntL[dl], 1);
        col[s0 + exclL[dl] + r] = (int)((unsigned)p >> 8);
    }
}

// ---------------- GEMM (+ fused attention scalars): 64 rows/block ----------------
// W staged in LDS (R10 lesson: global-W puts ~200cy L2 latency on the FMA
// critical path — LDS staging is load-bearing). Split-K: two 32KB half-tiles
// instead of one 64KB tile → 4 blocks/CU instead of 2 for latency hiding.

__global__ __launch_bounds__(256) void k_gemm(const float* __restrict__ A,
                                              const float* __restrict__ W,
                                              unsigned short* __restrict__ out,
                                              const float* __restrict__ att_s,
                                              const float* __restrict__ att_d,
                                              float* __restrict__ asrc,
                                              float* __restrict__ adst, int nrows) {
    __shared__ float Ws[64 * FDIM];          // 32 KB half-tile
    __shared__ float sAs[FDIM], sAd[FDIM];
    int t = threadIdx.x;
    if (t < FDIM) { sAs[t] = att_s[t]; sAd[t] = att_d[t]; }

    int tx = t & 31;
    int ty = t >> 5;
    int row0 = blockIdx.x * 64 + ty * 8;

    float acc[8][4];
#pragma unroll
    for (int i = 0; i < 8; ++i)
#pragma unroll
        for (int j = 0; j < 4; ++j) acc[i][j] = 0.f;

    int rr[8];
#pragma unroll
    for (int i = 0; i < 8; ++i)
        rr[i] = (row0 + i < nrows) ? (row0 + i) : (nrows - 1);

    for (int half = 0; half < 2; ++half) {
        __syncthreads();   // protect Ws reuse (and orders sAs write on half=0)
        for (int f = t; f < 64 * FDIM / 4; f += 256)
            ((float4*)Ws)[f] = ((const float4*)W)[half * (64 * FDIM / 4) + f];
        __syncthreads();

        int kbase = half * 64;
#pragma unroll 2
        for (int k4 = 0; k4 < 64; k4 += 4) {
            float4 xv[8];
#pragma unroll
            for (int i = 0; i < 8; ++i)
                xv[i] = *(const float4*)(A + (size_t)rr[i] * FDIM + kbase + k4);
#pragma unroll
            for (int q = 0; q < 4; ++q) {
                float4 wv = *(float4*)&Ws[(k4 + q) * FDIM + tx * 4];
#pragma unroll
                for (int i = 0; i < 8; ++i) {
                    float xs = (q == 0) ? xv[i].x : (q == 1) ? xv[i].y : (q == 2) ? xv[i].z : xv[i].w;
                    acc[i][0] = fmaf(xs, wv.x, acc[i][0]);
                    acc[i][1] = fmaf(xs, wv.y, acc[i][1]);
                    acc[i][2] = fmaf(xs, wv.z, acc[i][2]);
                    acc[i][3] = fmaf(xs, wv.w, acc[i][3]);
                }
            }
        }
    }

#pragma unroll
    for (int i = 0; i < 8; ++i) {
        if (row0 + i < nrows) {
            ushort4 o;
            o.x = f2bf(acc[i][0]);
            o.y = f2bf(acc[i][1]);
            o.z = f2bf(acc[i][2]);
            o.w = f2bf(acc[i][3]);
            *(ushort4*)(out + (size_t)(row0 + i) * FDIM + tx * 4) = o;
        }
    }

    float ps[8], pd[8];
#pragma unroll
    for (int i = 0; i < 8; ++i) {
        float s = 0.f, d = 0.f;
#pragma unroll
        for (int j = 0; j < 4; ++j) {
            s = fmaf(acc[i][j], sAs[tx * 4 + j], s);
            d = fmaf(acc[i][j], sAd[tx * 4 + j], d);
        }
        ps[i] = s; pd[i] = d;
    }
#pragma unroll
    for (int off = 8; off; off >>= 1) {
#pragma unroll
        for (int i = 0; i < 8; ++i) {
            ps[i] += __shfl_xor(ps[i], off);
            pd[i] += __shfl_xor(pd[i], off);
        }
    }
    if ((tx & 15) == 0) {
        int head = tx >> 4;
#pragma unroll
        for (int i = 0; i < 8; ++i) {
            if (row0 + i < nrows) {
                asrc[2 * (row0 + i) + head] = ps[i];
                adst[2 * (row0 + i) + head] = pd[i];
            }
        }
    }
}

// ---------------- per-dst softmax + aggregation: ONE WAVE PER NODE ----------------
// Zero LDS; readlane broadcasts make gather addresses SGPR-based (R10 win).

__global__ __launch_bounds__(256) void k_aggregate(const unsigned short* __restrict__ h,
                                                   const float* __restrict__ asrc,
                                                   const float* __restrict__ adst,
                                                   const int* __restrict__ rowp,
                                                   const int* __restrict__ col,
                                                   const float* __restrict__ bias,
                                                   float* __restrict__ outbuf,
                                                   const float* __restrict__ fcW,
                                                   const float* __restrict__ fcb,
                                                   float* __restrict__ outfin, int n) {
    int t = threadIdx.x;
    int w = t >> 6;
    int lane = t & 63;
    int node = blockIdx.x * 4 + w;      // uniform per wave
    if (node >= n) return;

    int start = rowp[node];
    int deg = rowp[node + 1] - start;
    float2 adv = *(const float2*)(adst + 2 * node);
    const ushort2* __restrict__ hb = (const ushort2*)h;
    bool head1 = lane >= 32;

    float m0 = -1e30f, m1 = -1e30f;
    float p0 = 0.f, p1 = 0.f;
    float accx = 0.f, accy = 0.f;

    for (int base = 0; base < deg; base += 64) {
        int cnt = min(64, deg - base);
        int s = 0;
        float v0 = -1e30f, v1 = -1e30f;
        if (lane < cnt) {
            s = col[start + base + lane];
            float2 av = *(const float2*)(asrc + 2 * s);
            v0 = lrelu(av.x + adv.x);
            v1 = lrelu(av.y + adv.y);
        }
        float c0 = v0, c1 = v1;
#pragma unroll
        for (int off = 32; off; off >>= 1) {
            c0 = fmaxf(c0, __shfl_xor(c0, off));
            c1 = fmaxf(c1, __shfl_xor(c1, off));
        }
        float nm0 = fmaxf(m0, c0), nm1 = fmaxf(m1, c1);
        float r0 = __expf(m0 - nm0), r1 = __expf(m1 - nm1);
        m0 = nm0; m1 = nm1;
        p0 *= r0; p1 *= r1;
        float rmy = head1 ? r1 : r0;
        accx *= rmy; accy *= rmy;
        float e0 = (lane < cnt) ? __expf(v0 - m0) : 0.f;
        float e1 = (lane < cnt) ? __expf(v1 - m1) : 0.f;
        p0 += e0; p1 += e1;
        int ie0 = __float_as_int(e0);
        int ie1 = __float_as_int(e1);

        float2 g0 = make_float2(0.f, 0.f), g1 = make_float2(0.f, 0.f);
        float2 g2 = make_float2(0.f, 0.f), g3 = make_float2(0.f, 0.f);
        int i = 0;
        for (; i + 3 < cnt; i += 4) {
            unsigned sa = (unsigned)__builtin_amdgcn_readlane(s, i);
            unsigned sb = (unsigned)__builtin_amdgcn_readlane(s, i + 1);
            unsigned sc = (unsigned)__builtin_amdgcn_readlane(s, i + 2);
            unsigned sd = (unsigned)__builtin_amdgcn_readlane(s, i + 3);
            ushort2 ha = hb[sa * 64u + lane];
            ushort2 hv = hb[sb * 64u + lane];
            ushort2 hc = hb[sc * 64u + lane];
            ushort2 hd = hb[sd * 64u + lane];
            float wa = head1 ? __int_as_float(__builtin_amdgcn_readlane(ie1, i))
                             : __int_as_float(__builtin_amdgcn_readlane(ie0, i));
            float wb = head1 ? __int_as_float(__builtin_amdgcn_readlane(ie1, i + 1))
                             : __int_as_float(__builtin_amdgcn_readlane(ie0, i + 1));
            float wc = head1 ? __int_as_float(__builtin_amdgcn_readlane(ie1, i + 2))
                             : __int_as_float(__builtin_amdgcn_readlane(ie0, i + 2));
            float wd = head1 ? __int_as_float(__builtin_amdgcn_readlane(ie1, i + 3))
                             : __int_as_float(__builtin_amdgcn_readlane(ie0, i + 3));
            g0.x = fmaf(bf2f(ha.x), wa, g0.x); g0.y = fmaf(bf2f(ha.y), wa, g0.y);
            g1.x = fmaf(bf2f(hv.x), wb, g1.x); g1.y = fmaf(bf2f(hv.y), wb, g1.y);
            g2.x = fmaf(bf2f(hc.x), wc, g2.x); g2.y = fmaf(bf2f(hc.y), wc, g2.y);
            g3.x = fmaf(bf2f(hd.x), wd, g3.x); g3.y = fmaf(bf2f(hd.y), wd, g3.y);
        }
        for (; i < cnt; ++i) {
            unsigned sv = (unsigned)__builtin_amdgcn_readlane(s, i);
            float a = head1 ? __int_as_float(__builtin_amdgcn_readlane(ie1, i))
                            : __int_as_float(__builtin_amdgcn_readlane(ie0, i));
            ushort2 hv = hb[sv * 64u + lane];
            g0.x = fmaf(bf2f(hv.x), a, g0.x);
            g0.y = fmaf(bf2f(hv.y), a, g0.y);
        }
        accx += g0.x + g1.x + g2.x + g3.x;
        accy += g0.y + g1.y + g2.y + g3.y;
    }

#pragma unroll
    for (int off = 32; off; off >>= 1) {
        p0 += __shfl_xor(p0, off);
        p1 += __shfl_xor(p1, off);
    }
    float invmy = head1 ? 1.f / (p1 + 1e-16f) : 1.f / (p0 + 1e-16f);
    accx *= invmy;
    accy *= invmy;

    int c0i = 2 * lane, c1i = 2 * lane + 1;
    float2 bv = *(const float2*)(bias + c0i);
    float o0 = fmaxf(accx + bv.x, 0.f);
    float o1 = fmaxf(accy + bv.y, 0.f);
    if (outbuf)
        *(float2*)(outbuf + (size_t)node * FDIM + c0i) = make_float2(o0, o1);
    if (outfin) {
        float2 fv = *(const float2*)(fcW + c0i);
        float p = fmaf(o0, fv.x, o1 * fv.y);
#pragma unroll
        for (int off = 32; off; off >>= 1) p += __shfl_xor(p, off);
        if (lane == 0) outfin[node] = 1.f / (1.f + __expf(-(p + fcb[0])));
    }
}

// ---------------- host ----------------

static inline size_t rnd256(size_t x) { return (x + 255) & ~(size_t)255; }

extern "C" void kernel_launch(void* const* d_in, const int* in_sizes, int n_in,
                              void* d_out, int out_size, void* d_ws, size_t ws_size,
                              hipStream_t stream) {
    const float* x    = (const float*)d_in[0];
    const int*   ei   = (const int*)d_in[1];
    const float* W1   = (const float*)d_in[3];
    const float* as1  = (const float*)d_in[4];
    const float* ad1  = (const float*)d_in[5];
    const float* b1   = (const float*)d_in[6];
    const float* W2   = (const float*)d_in[7];
    const float* as2  = (const float*)d_in[8];
    const float* ad2  = (const float*)d_in[9];
    const float* b2   = (const float*)d_in[10];
    const float* fcW  = (const float*)d_in[11];
    const float* fcb  = (const float*)d_in[12];

    int N = in_sizes[0] / FDIM;
    int E = in_sizes[2];
    int E2 = E + N;
    const int* srcp = ei;
    const int* dstp = ei + E;

    int nb1   = (E2 + 1023) / 1024;        // radix blocks (1024 edges each)
    int nbuck = (N + 255) / 256;           // coarse buckets (256 dsts each)
    int M     = nbuck * nb1;               // hist entries

    char* w = (char*)d_ws;
    unsigned short* hbuf = (unsigned short*)w; w += rnd256((size_t)N * FDIM * sizeof(unsigned short));
    float* obuf = (float*)w;  w += rnd256((size_t)N * FDIM * sizeof(float));
    float* asrc = (float*)w;  w += rnd256((size_t)N * 2 * sizeof(float));
    float* adst = (float*)w;  w += rnd256((size_t)N * 2 * sizeof(float));
    int* rowp = (int*)w;      w += rnd256((size_t)(N + 1) * sizeof(int));
    int* bsum = (int*)w;      w += rnd256((size_t)((M + 1023) / 1024) * sizeof(int));
    int* hist = (int*)w;      w += rnd256((size_t)M * sizeof(int));
    int* part = (int*)w;      w += rnd256((size_t)E2 * sizeof(int));
    int* col  = (int*)w;      w += rnd256((size_t)E2 * sizeof(int));

    int ggrid = (N + 63) / 64;
    int agrid = (N + 3) / 4;
    int sblk  = (M + 1023) / 1024;

    // atomic-free CSR build
    k_hist<<<nb1, 256, 0, stream>>>(dstp, E, N, hist, nb1, nbuck);
    k_scan1<<<sblk, 256, 0, stream>>>(hist, hist, bsum, M);
    k_scan2<<<1, 256, 0, stream>>>(bsum, sblk);
    k_scan3<<<(M + 255) / 256, 256, 0, stream>>>(hist, bsum, M);
    k_scatter<<<nb1, 256, 0, stream>>>(srcp, dstp, E, N, hist, nb1, nbuck, part);
    k_bucket<<<nbuck, 256, 0, stream>>>(part, hist, nb1, nbuck, E2, N, rowp, col);

    // layer 1 (gemm + fused att scalars; bf16 h)
    k_gemm<<<ggrid, 256, 0, stream>>>(x, W1, hbuf, as1, ad1, asrc, adst, N);
    k_aggregate<<<agrid, 256, 0, stream>>>(hbuf, asrc, adst, rowp, col, b1,
                                           obuf, nullptr, nullptr, nullptr, N);

    // layer 2 (fc + sigmoid fused into epilogue)
    k_gemm<<<ggrid, 256, 0, stream>>>(obuf, W2, hbuf, as2, ad2, asrc, adst, N);
    k_aggregate<<<agrid, 256, 0, stream>>>(hbuf, asrc, adst, rowp, col, b2,
                                           nullptr, fcW, fcb, (float*)d_out, N);
}